// Round 11
// baseline (312.908 us; speedup 1.0000x reference)
//
#include <hip/hip_runtime.h>
#include <hip/hip_bf16.h>
#include <cstdint>
#include <cstddef>

#define N_ROWS 8192
#define DIM    512
#define NKT    8          // K-tiles of 64
#define NBLK   1024       // gemm grid
#define C_EXPSCALE 14.4269504088896340736f   // 10*log2(e); exp(sim-10)=exp2((cos-1)*this)

typedef __attribute__((ext_vector_type(8))) short bf16x8;
typedef __attribute__((ext_vector_type(4))) float f32x4;

__device__ __forceinline__ ushort f2bf(float x) {
  union { float f; uint32_t u; } c; c.f = x;
  uint32_t r = (c.u + 0x7fffu + ((c.u >> 16) & 1u)) >> 16;
  return (ushort)r;
}

// ---------------- prep: fp32 row norms, fp32 diag, bf16 normalized copies ----
__global__ __launch_bounds__(256) void prep_kernel(const float* __restrict__ V,
                                                   const float* __restrict__ U,
                                                   ushort* __restrict__ Vn,
                                                   ushort* __restrict__ Un,
                                                   float* __restrict__ diag,
                                                   float* __restrict__ row_sum,
                                                   float* __restrict__ col_sum,
                                                   int* __restrict__ ticket) {
  if (blockIdx.x == 0 && threadIdx.x == 0) *ticket = 0;
  const int row = blockIdx.x * 4 + (threadIdx.x >> 6);
  const int l = threadIdx.x & 63;
  const float4* v4 = (const float4*)(V + (size_t)row * DIM) + l * 2;
  const float4* u4 = (const float4*)(U + (size_t)row * DIM) + l * 2;
  float4 a0 = v4[0], a1 = v4[1];
  float4 b0 = u4[0], b1 = u4[1];
  float sv = a0.x*a0.x + a0.y*a0.y + a0.z*a0.z + a0.w*a0.w
           + a1.x*a1.x + a1.y*a1.y + a1.z*a1.z + a1.w*a1.w;
  float su = b0.x*b0.x + b0.y*b0.y + b0.z*b0.z + b0.w*b0.w
           + b1.x*b1.x + b1.y*b1.y + b1.z*b1.z + b1.w*b1.w;
  float sd = a0.x*b0.x + a0.y*b0.y + a0.z*b0.z + a0.w*b0.w
           + a1.x*b1.x + a1.y*b1.y + a1.z*b1.z + a1.w*b1.w;
#pragma unroll
  for (int m = 1; m < 64; m <<= 1) {
    sv += __shfl_xor(sv, m, 64);
    su += __shfl_xor(su, m, 64);
    sd += __shfl_xor(sd, m, 64);
  }
  const float rv = 1.0f / fmaxf(sqrtf(sv), 1e-8f);
  const float ru = 1.0f / fmaxf(sqrtf(su), 1e-8f);
  if (l == 0) {
    diag[row] = sd * rv * ru * 10.0f;
    row_sum[row] = 0.0f;
    col_sum[row] = 0.0f;
  }

  const float av[8] = {a0.x, a0.y, a0.z, a0.w, a1.x, a1.y, a1.z, a1.w};
  const float bv[8] = {b0.x, b0.y, b0.z, b0.w, b1.x, b1.y, b1.z, b1.w};
  union { ushort us[8]; uint4 q; } pv, pu;
#pragma unroll
  for (int j = 0; j < 8; ++j) {
    pv.us[j] = f2bf(av[j] * rv);
    pu.us[j] = f2bf(bv[j] * ru);
  }
  *(uint4*)(Vn + (size_t)row * DIM + l * 8) = pv.q;
  *(uint4*)(Un + (size_t)row * DIM + l * 8) = pu.q;
}

// ---- 256x256 GEMM (bf16 MFMA) + exp(sim-10) + row/col sums + FUSED finalize ----
// K-loop byte-identical to R10 (16 waves / 4 per SIMD, single-barrier
// boundary, L2-residency map). New: finalize fused via ticket -- each block:
// device-scope atomics -> __threadfence() -> atomicAdd(ticket); the block
// drawing ticket NBLK-1 performs the final LSE reduction. Cross-XCD
// coherence: last block reads row/col sums via atomicAdd(p, 0.0f)
// (coherent-point reads; plain loads could hit a stale local L2 -- G16).
// diag is prep-written (kernel-boundary visible): plain reads OK.
__global__ __launch_bounds__(1024, 4) void gemm_lse_kernel(const ushort* __restrict__ Vn,
                                                           const ushort* __restrict__ Un,
                                                           float* __restrict__ row_sum,
                                                           float* __restrict__ col_sum,
                                                           const float* __restrict__ diag,
                                                           int* __restrict__ ticket,
                                                           float* __restrict__ out) {
  // buf b at b*65536: A[256][64] @0 (32K), B[256][64] @32768 (32K)
  __shared__ ushort Tile[65536];   // 128 KiB

  const int tid  = threadIdx.x;
  const int lane = tid & 63;
  const int wid  = tid >> 6;       // 0..15
  const int wr   = wid >> 2;       // 0..3 (64-row band)
  const int wc   = wid & 3;        // 0..3 (64-col band)
  const int l15  = lane & 15;
  const int lhi  = lane >> 4;      // 0..3
  const int sw7  = l15 & 7;

  // L2-residency map (R6): xcd owns fixed 4-ct stripe; rt streams 8/round
  const int bid  = blockIdx.x;
  const int xcd  = bid & 7;
  const int x    = bid >> 3;               // 0..127
  const int rt   = x >> 2;                 // 0..31
  const int ct   = xcd * 4 + (x & 3);      // fixed stripe
  const int br   = rt << 8;
  const int bc   = ct << 8;

  // ---- staging geometry: per matrix per K-tile = 2 issues x 1024 thr x 16B ----
  const int rr  = tid >> 3;                // 0..127
  const int seg = (tid & 7) ^ (rr & 7);    // inverse-swizzled source seg
  const ushort* gA[2]; const ushort* gB[2];
#pragma unroll
  for (int i = 0; i < 2; ++i) {
    gA[i] = Vn + (size_t)(br + i * 128 + rr) * DIM + seg * 8;
    gB[i] = Un + (size_t)(bc + i * 128 + rr) * DIM + seg * 8;
  }

  auto stg4 = [&](int buf, int kt) {   // whole K-tile kt -> buf (4 glds/thread)
#pragma unroll
    for (int i = 0; i < 2; ++i)
      __builtin_amdgcn_global_load_lds(
          (const __attribute__((address_space(1))) unsigned int*)(gA[i] + kt * 64),
          (__attribute__((address_space(3))) unsigned int*)((char*)Tile + buf * 65536 + i * 16384 + wid * 1024),
          16, 0, 0);
#pragma unroll
    for (int i = 0; i < 2; ++i)
      __builtin_amdgcn_global_load_lds(
          (const __attribute__((address_space(1))) unsigned int*)(gB[i] + kt * 64),
          (__attribute__((address_space(3))) unsigned int*)((char*)Tile + buf * 65536 + 32768 + i * 16384 + wid * 1024),
          16, 0, 0);
  };

  // ---- LDS read bases; physical slot = ((kk<<2)|lhi) ^ sw7 ----
  const char* TB = (const char*)Tile;
  const int sl0  = ((0 | lhi) ^ sw7) * 16;
  const int sl1  = ((4 | lhi) ^ sw7) * 16;
  const int aoff = (wr * 64 + l15) * 128;
  const int boff = (wc * 64 + l15) * 128;
  const char* pA[2] = { TB + aoff,          TB + 65536 + aoff };
  const char* pB[2] = { TB + 32768 + boff,  TB + 98304 + boff };

  f32x4 acc[4][4];
#pragma unroll
  for (int m = 0; m < 4; ++m)
#pragma unroll
    for (int n = 0; n < 4; ++n) acc[m][n] = (f32x4){0.f, 0.f, 0.f, 0.f};

  // prologue: tiles 0,1 staged (8 glds); tile0 landed at vmcnt(4)
  stg4(0, 0); stg4(1, 1);
  asm volatile("s_waitcnt vmcnt(4)" ::: "memory");
  __builtin_amdgcn_s_barrier();
  asm volatile("" ::: "memory");

#pragma unroll
  for (int j = 0; j < NKT; ++j) {
    const int b = j & 1;

    bf16x8 A0[4], B0[4], A1[4], B1[4];
    // kk0: read + 16 MFMA (compiler interleaves with counted lgkm)
#pragma unroll
    for (int m = 0; m < 4; ++m) A0[m] = *(const bf16x8*)(pA[b] + m * 2048 + sl0);
#pragma unroll
    for (int n = 0; n < 4; ++n) B0[n] = *(const bf16x8*)(pB[b] + n * 2048 + sl0);
    __builtin_amdgcn_s_setprio(1);
#pragma unroll
    for (int m = 0; m < 4; ++m)
#pragma unroll
      for (int n = 0; n < 4; ++n)
        acc[m][n] = __builtin_amdgcn_mfma_f32_16x16x32_bf16(A0[m], B0[n], acc[m][n], 0, 0, 0);
    __builtin_amdgcn_s_setprio(0);

    // kk1: read + 16 MFMA
#pragma unroll
    for (int m = 0; m < 4; ++m) A1[m] = *(const bf16x8*)(pA[b] + m * 2048 + sl1);
#pragma unroll
    for (int n = 0; n < 4; ++n) B1[n] = *(const bf16x8*)(pB[b] + n * 2048 + sl1);
    __builtin_amdgcn_s_setprio(1);
#pragma unroll
    for (int m = 0; m < 4; ++m)
#pragma unroll
      for (int n = 0; n < 4; ++n)
        acc[m][n] = __builtin_amdgcn_mfma_f32_16x16x32_bf16(A1[m], B1[n], acc[m][n], 0, 0, 0);
    __builtin_amdgcn_s_setprio(0);

    // ---- single-barrier boundary ----
    if (j + 2 < NKT) {
      asm volatile("s_waitcnt vmcnt(0) lgkmcnt(0)" ::: "memory");  // cold: loads 1 K-tile old + this tile's reads
      __builtin_amdgcn_s_barrier();
      asm volatile("" ::: "memory");
      stg4(b, j + 2);                                              // WAR-safe after bar; flies across next tile
    } else if (j == NKT - 2) {
      asm volatile("s_waitcnt vmcnt(0) lgkmcnt(0)" ::: "memory");  // tile 7 landed
      __builtin_amdgcn_s_barrier();
      asm volatile("" ::: "memory");
    }
    // j == NKT-1: fall through to epilogue
  }

  // ---- epilogue: exp(sim-10), row/col partial sums ----
  float* Red = (float*)Tile;

#pragma unroll
  for (int m = 0; m < 4; ++m)
#pragma unroll
    for (int n = 0; n < 4; ++n) {
      f32x4 v = acc[m][n];
#pragma unroll
      for (int r = 0; r < 4; ++r) v[r] = __builtin_amdgcn_exp2f((v[r] - 1.0f) * C_EXPSCALE);
      acc[m][n] = v;
    }

  __syncthreads();   // all frag reads done before Red overwrites Tile

  // rows: row_local = wr*64 + m*16 + lhi*4 + r; sum over wave's 64 cols
#pragma unroll
  for (int m = 0; m < 4; ++m)
#pragma unroll
    for (int r = 0; r < 4; ++r) {
      float s = acc[m][0][r] + acc[m][1][r] + acc[m][2][r] + acc[m][3][r];
      s += __shfl_xor(s, 1, 64);
      s += __shfl_xor(s, 2, 64);
      s += __shfl_xor(s, 4, 64);
      s += __shfl_xor(s, 8, 64);
      if (l15 == 0) Red[wc * 256 + wr * 64 + m * 16 + lhi * 4 + r] = s;
    }
  // cols: col_local = wc*64 + n*16 + l15; sum over wave's 64 rows
#pragma unroll
  for (int n = 0; n < 4; ++n) {
    float s = 0.f;
#pragma unroll
    for (int m = 0; m < 4; ++m)
      s += acc[m][n][0] + acc[m][n][1] + acc[m][n][2] + acc[m][n][3];
    s += __shfl_xor(s, 16, 64);
    s += __shfl_xor(s, 32, 64);
    if (lane < 16) Red[1024 + wr * 256 + wc * 64 + n * 16 + lane] = s;
  }
  __syncthreads();

  if (tid < 256) {
    float s = Red[tid] + Red[256 + tid] + Red[512 + tid] + Red[768 + tid];
    atomicAdd(&row_sum[br + tid], s);
  } else if (tid < 512) {
    const int c = tid - 256;
    float s = Red[1024 + c] + Red[1280 + c] + Red[1536 + c] + Red[1792 + c];
    atomicAdd(&col_sum[bc + c], s);
  }

  // ---- fused finalize: last block to finish reduces the loss ----
  __threadfence();                       // order this block's atomics before ticket
  __shared__ int lastFlag;
  if (tid == 0) lastFlag = (atomicAdd(ticket, 1) == NBLK - 1);
  __syncthreads();
  if (!lastFlag) return;

  float facc = 0.0f;
  for (int i = tid; i < N_ROWS; i += 1024) {
    const float rs = atomicAdd(&row_sum[i], 0.0f);   // coherent-point read (cross-XCD)
    const float cs = atomicAdd(&col_sum[i], 0.0f);
    facc += 0.75f * (10.0f + logf(rs)) + 0.25f * (10.0f + logf(cs)) - diag[i];
  }
  __syncthreads();                       // Red region free for reuse
  Red[tid] = facc;
  __syncthreads();
  for (int s = 512; s > 0; s >>= 1) {
    if (tid < s) Red[tid] += Red[tid + s];
    __syncthreads();
  }
  if (tid == 0) out[0] = Red[0] / (float)N_ROWS;
}

extern "C" void kernel_launch(void* const* d_in, const int* in_sizes, int n_in,
                              void* d_out, int out_size, void* d_ws, size_t ws_size,
                              hipStream_t stream) {
  const float* V = (const float*)d_in[0];
  const float* U = (const float*)d_in[1];
  float* out = (float*)d_out;

  char* ws = (char*)d_ws;
  ushort* Vn      = (ushort*)(ws);
  ushort* Un      = (ushort*)(ws + 8388608);
  float*  diag    = (float*)(ws + 16777216);
  float*  row_sum = (float*)(ws + 16777216 + 32768);
  float*  col_sum = (float*)(ws + 16777216 + 65536);
  int*    ticket  = (int*)(ws + 16777216 + 98304);

  prep_kernel<<<N_ROWS / 4, 256, 0, stream>>>(V, U, Vn, Un, diag, row_sum, col_sum, ticket);
  gemm_lse_kernel<<<NBLK, 1024, 0, stream>>>(Vn, Un, row_sum, col_sum, diag, ticket, out);
}

// Round 12
// 91.093 us; speedup vs baseline: 3.4350x; 3.4350x over previous
//
#include <hip/hip_runtime.h>
#include <hip/hip_bf16.h>
#include <cstdint>
#include <cstddef>

#define N_ROWS 8192
#define DIM    512
#define NKT    8          // K-tiles of 64
#define NBLK   1024       // gemm grid
#define C_EXPSCALE 14.4269504088896340736f   // 10*log2(e); exp(sim-10)=exp2((cos-1)*this)

typedef __attribute__((ext_vector_type(8))) short bf16x8;
typedef __attribute__((ext_vector_type(4))) float f32x4;

__device__ __forceinline__ ushort f2bf(float x) {
  union { float f; uint32_t u; } c; c.f = x;
  uint32_t r = (c.u + 0x7fffu + ((c.u >> 16) & 1u)) >> 16;
  return (ushort)r;
}

// ---------------- prep: fp32 row norms, fp32 diag, bf16 normalized copies ----
__global__ __launch_bounds__(256) void prep_kernel(const float* __restrict__ V,
                                                   const float* __restrict__ U,
                                                   ushort* __restrict__ Vn,
                                                   ushort* __restrict__ Un,
                                                   float* __restrict__ diag,
                                                   float* __restrict__ row_sum,
                                                   float* __restrict__ col_sum,
                                                   int* __restrict__ ticket) {
  if (blockIdx.x == 0 && threadIdx.x == 0) *ticket = 0;
  const int row = blockIdx.x * 4 + (threadIdx.x >> 6);
  const int l = threadIdx.x & 63;
  const float4* v4 = (const float4*)(V + (size_t)row * DIM) + l * 2;
  const float4* u4 = (const float4*)(U + (size_t)row * DIM) + l * 2;
  float4 a0 = v4[0], a1 = v4[1];
  float4 b0 = u4[0], b1 = u4[1];
  float sv = a0.x*a0.x + a0.y*a0.y + a0.z*a0.z + a0.w*a0.w
           + a1.x*a1.x + a1.y*a1.y + a1.z*a1.z + a1.w*a1.w;
  float su = b0.x*b0.x + b0.y*b0.y + b0.z*b0.z + b0.w*b0.w
           + b1.x*b1.x + b1.y*b1.y + b1.z*b1.z + b1.w*b1.w;
  float sd = a0.x*b0.x + a0.y*b0.y + a0.z*b0.z + a0.w*b0.w
           + a1.x*b1.x + a1.y*b1.y + a1.z*b1.z + a1.w*b1.w;
#pragma unroll
  for (int m = 1; m < 64; m <<= 1) {
    sv += __shfl_xor(sv, m, 64);
    su += __shfl_xor(su, m, 64);
    sd += __shfl_xor(sd, m, 64);
  }
  const float rv = 1.0f / fmaxf(sqrtf(sv), 1e-8f);
  const float ru = 1.0f / fmaxf(sqrtf(su), 1e-8f);
  if (l == 0) {
    diag[row] = sd * rv * ru * 10.0f;
    row_sum[row] = 0.0f;
    col_sum[row] = 0.0f;
  }

  const float av[8] = {a0.x, a0.y, a0.z, a0.w, a1.x, a1.y, a1.z, a1.w};
  const float bv[8] = {b0.x, b0.y, b0.z, b0.w, b1.x, b1.y, b1.z, b1.w};
  union { ushort us[8]; uint4 q; } pv, pu;
#pragma unroll
  for (int j = 0; j < 8; ++j) {
    pv.us[j] = f2bf(av[j] * rv);
    pu.us[j] = f2bf(bv[j] * ru);
  }
  *(uint4*)(Vn + (size_t)row * DIM + l * 8) = pv.q;
  *(uint4*)(Un + (size_t)row * DIM + l * 8) = pu.q;
}

// ---- 256x256 GEMM (bf16 MFMA) + exp(sim-10) + row/col sums + fused finalize ----
// K-loop byte-identical to R10. Fused finalize WITHOUT __threadfence (R11's
// agent-scope fence = L2 writeback/invalidate per block -> nuked the
// L2-resident panels for co-resident blocks -> 4.3x slowdown, G16 trap).
// Fence-free protocol: sum atomics are device-scope RMWs performed at the
// coherent point; __syncthreads() drains each wave's vmcnt (atomics acked)
// before any wave passes; then ONE ticket RMW by tid 0. Last block reads the
// sums via atomicAdd(p, 0.0f) RMWs (coherent point, never stale local L2).
__global__ __launch_bounds__(1024, 4) void gemm_lse_kernel(const ushort* __restrict__ Vn,
                                                           const ushort* __restrict__ Un,
                                                           float* __restrict__ row_sum,
                                                           float* __restrict__ col_sum,
                                                           const float* __restrict__ diag,
                                                           int* __restrict__ ticket,
                                                           float* __restrict__ out) {
  // buf b at b*65536: A[256][64] @0 (32K), B[256][64] @32768 (32K)
  __shared__ ushort Tile[65536];   // 128 KiB (flag + Red live inside)

  const int tid  = threadIdx.x;
  const int lane = tid & 63;
  const int wid  = tid >> 6;       // 0..15
  const int wr   = wid >> 2;       // 0..3 (64-row band)
  const int wc   = wid & 3;        // 0..3 (64-col band)
  const int l15  = lane & 15;
  const int lhi  = lane >> 4;      // 0..3
  const int sw7  = l15 & 7;

  // L2-residency map (R6): xcd owns fixed 4-ct stripe; rt streams 8/round
  const int bid  = blockIdx.x;
  const int xcd  = bid & 7;
  const int x    = bid >> 3;               // 0..127
  const int rt   = x >> 2;                 // 0..31
  const int ct   = xcd * 4 + (x & 3);      // fixed stripe
  const int br   = rt << 8;
  const int bc   = ct << 8;

  // ---- staging geometry: per matrix per K-tile = 2 issues x 1024 thr x 16B ----
  const int rr  = tid >> 3;                // 0..127
  const int seg = (tid & 7) ^ (rr & 7);    // inverse-swizzled source seg
  const ushort* gA[2]; const ushort* gB[2];
#pragma unroll
  for (int i = 0; i < 2; ++i) {
    gA[i] = Vn + (size_t)(br + i * 128 + rr) * DIM + seg * 8;
    gB[i] = Un + (size_t)(bc + i * 128 + rr) * DIM + seg * 8;
  }

  auto stg4 = [&](int buf, int kt) {   // whole K-tile kt -> buf (4 glds/thread)
#pragma unroll
    for (int i = 0; i < 2; ++i)
      __builtin_amdgcn_global_load_lds(
          (const __attribute__((address_space(1))) unsigned int*)(gA[i] + kt * 64),
          (__attribute__((address_space(3))) unsigned int*)((char*)Tile + buf * 65536 + i * 16384 + wid * 1024),
          16, 0, 0);
#pragma unroll
    for (int i = 0; i < 2; ++i)
      __builtin_amdgcn_global_load_lds(
          (const __attribute__((address_space(1))) unsigned int*)(gB[i] + kt * 64),
          (__attribute__((address_space(3))) unsigned int*)((char*)Tile + buf * 65536 + 32768 + i * 16384 + wid * 1024),
          16, 0, 0);
  };

  // ---- LDS read bases; physical slot = ((kk<<2)|lhi) ^ sw7 ----
  const char* TB = (const char*)Tile;
  const int sl0  = ((0 | lhi) ^ sw7) * 16;
  const int sl1  = ((4 | lhi) ^ sw7) * 16;
  const int aoff = (wr * 64 + l15) * 128;
  const int boff = (wc * 64 + l15) * 128;
  const char* pA[2] = { TB + aoff,          TB + 65536 + aoff };
  const char* pB[2] = { TB + 32768 + boff,  TB + 98304 + boff };

  f32x4 acc[4][4];
#pragma unroll
  for (int m = 0; m < 4; ++m)
#pragma unroll
    for (int n = 0; n < 4; ++n) acc[m][n] = (f32x4){0.f, 0.f, 0.f, 0.f};

  // prologue: tiles 0,1 staged (8 glds); tile0 landed at vmcnt(4)
  stg4(0, 0); stg4(1, 1);
  asm volatile("s_waitcnt vmcnt(4)" ::: "memory");
  __builtin_amdgcn_s_barrier();
  asm volatile("" ::: "memory");

#pragma unroll
  for (int j = 0; j < NKT; ++j) {
    const int b = j & 1;

    bf16x8 A0[4], B0[4], A1[4], B1[4];
    // kk0: read + 16 MFMA (compiler interleaves with counted lgkm)
#pragma unroll
    for (int m = 0; m < 4; ++m) A0[m] = *(const bf16x8*)(pA[b] + m * 2048 + sl0);
#pragma unroll
    for (int n = 0; n < 4; ++n) B0[n] = *(const bf16x8*)(pB[b] + n * 2048 + sl0);
    __builtin_amdgcn_s_setprio(1);
#pragma unroll
    for (int m = 0; m < 4; ++m)
#pragma unroll
      for (int n = 0; n < 4; ++n)
        acc[m][n] = __builtin_amdgcn_mfma_f32_16x16x32_bf16(A0[m], B0[n], acc[m][n], 0, 0, 0);
    __builtin_amdgcn_s_setprio(0);

    // kk1: read + 16 MFMA
#pragma unroll
    for (int m = 0; m < 4; ++m) A1[m] = *(const bf16x8*)(pA[b] + m * 2048 + sl1);
#pragma unroll
    for (int n = 0; n < 4; ++n) B1[n] = *(const bf16x8*)(pB[b] + n * 2048 + sl1);
    __builtin_amdgcn_s_setprio(1);
#pragma unroll
    for (int m = 0; m < 4; ++m)
#pragma unroll
      for (int n = 0; n < 4; ++n)
        acc[m][n] = __builtin_amdgcn_mfma_f32_16x16x32_bf16(A1[m], B1[n], acc[m][n], 0, 0, 0);
    __builtin_amdgcn_s_setprio(0);

    // ---- single-barrier boundary ----
    if (j + 2 < NKT) {
      asm volatile("s_waitcnt vmcnt(0) lgkmcnt(0)" ::: "memory");  // cold: loads 1 K-tile old + this tile's reads
      __builtin_amdgcn_s_barrier();
      asm volatile("" ::: "memory");
      stg4(b, j + 2);                                              // WAR-safe after bar; flies across next tile
    } else if (j == NKT - 2) {
      asm volatile("s_waitcnt vmcnt(0) lgkmcnt(0)" ::: "memory");  // tile 7 landed
      __builtin_amdgcn_s_barrier();
      asm volatile("" ::: "memory");
    }
    // j == NKT-1: fall through to epilogue
  }

  // ---- epilogue: exp(sim-10), row/col partial sums ----
  float* Red = (float*)Tile;

#pragma unroll
  for (int m = 0; m < 4; ++m)
#pragma unroll
    for (int n = 0; n < 4; ++n) {
      f32x4 v = acc[m][n];
#pragma unroll
      for (int r = 0; r < 4; ++r) v[r] = __builtin_amdgcn_exp2f((v[r] - 1.0f) * C_EXPSCALE);
      acc[m][n] = v;
    }

  __syncthreads();   // all frag reads done before Red overwrites Tile

  // rows: row_local = wr*64 + m*16 + lhi*4 + r; sum over wave's 64 cols
#pragma unroll
  for (int m = 0; m < 4; ++m)
#pragma unroll
    for (int r = 0; r < 4; ++r) {
      float s = acc[m][0][r] + acc[m][1][r] + acc[m][2][r] + acc[m][3][r];
      s += __shfl_xor(s, 1, 64);
      s += __shfl_xor(s, 2, 64);
      s += __shfl_xor(s, 4, 64);
      s += __shfl_xor(s, 8, 64);
      if (l15 == 0) Red[wc * 256 + wr * 64 + m * 16 + lhi * 4 + r] = s;
    }
  // cols: col_local = wc*64 + n*16 + l15; sum over wave's 64 rows
#pragma unroll
  for (int n = 0; n < 4; ++n) {
    float s = 0.f;
#pragma unroll
    for (int m = 0; m < 4; ++m)
      s += acc[m][n][0] + acc[m][n][1] + acc[m][n][2] + acc[m][n][3];
    s += __shfl_xor(s, 16, 64);
    s += __shfl_xor(s, 32, 64);
    if (lane < 16) Red[1024 + wr * 256 + wc * 64 + n * 16 + lane] = s;
  }
  __syncthreads();

  if (tid < 256) {
    float s = Red[tid] + Red[256 + tid] + Red[512 + tid] + Red[768 + tid];
    atomicAdd(&row_sum[br + tid], s);
  } else if (tid < 512) {
    const int c = tid - 256;
    float s = Red[1024 + c] + Red[1280 + c] + Red[1536 + c] + Red[1792 + c];
    atomicAdd(&col_sum[bc + c], s);
  }

  // ---- fence-free fused finalize ----
  // Each wave's sum atomics are acked at the device-coherent point before it
  // passes the barrier (__syncthreads drains vmcnt); then one ticket RMW.
  asm volatile("s_waitcnt vmcnt(0)" ::: "memory");
  __syncthreads();
  volatile int* flagp = (volatile int*)((char*)Tile + 16384);
  if (tid == 0) *flagp = (atomicAdd(ticket, 1) == NBLK - 1) ? 1 : 0;
  __syncthreads();
  if (!*flagp) return;

  // last block: read sums via atomic RMWs (coherent point, cross-XCD safe)
  float facc = 0.0f;
  for (int i = tid; i < N_ROWS; i += 1024) {
    const float rs = atomicAdd(&row_sum[i], 0.0f);
    const float cs = atomicAdd(&col_sum[i], 0.0f);
    facc += 0.75f * (10.0f + logf(rs)) + 0.25f * (10.0f + logf(cs)) - diag[i];
  }
  __syncthreads();
  Red[tid] = facc;
  __syncthreads();
  for (int s = 512; s > 0; s >>= 1) {
    if (tid < s) Red[tid] += Red[tid + s];
    __syncthreads();
  }
  if (tid == 0) out[0] = Red[0] / (float)N_ROWS;
}

extern "C" void kernel_launch(void* const* d_in, const int* in_sizes, int n_in,
                              void* d_out, int out_size, void* d_ws, size_t ws_size,
                              hipStream_t stream) {
  const float* V = (const float*)d_in[0];
  const float* U = (const float*)d_in[1];
  float* out = (float*)d_out;

  char* ws = (char*)d_ws;
  ushort* Vn      = (ushort*)(ws);
  ushort* Un      = (ushort*)(ws + 8388608);
  float*  diag    = (float*)(ws + 16777216);
  float*  row_sum = (float*)(ws + 16777216 + 32768);
  float*  col_sum = (float*)(ws + 16777216 + 65536);
  int*    ticket  = (int*)(ws + 16777216 + 98304);

  prep_kernel<<<N_ROWS / 4, 256, 0, stream>>>(V, U, Vn, Un, diag, row_sum, col_sum, ticket);
  gemm_lse_kernel<<<NBLK, 1024, 0, stream>>>(Vn, Un, row_sum, col_sum, diag, ticket, out);
}

// Round 13
// 86.239 us; speedup vs baseline: 3.6284x; 1.0563x over previous
//
#include <hip/hip_runtime.h>
#include <hip/hip_bf16.h>
#include <cstdint>
#include <cstddef>

#define N_ROWS 8192
#define DIM    512
#define NKT    8          // K-tiles of 64
#define C_EXPSCALE 14.4269504088896340736f   // 10*log2(e); exp(sim-10)=exp2((cos-1)*this)

typedef __attribute__((ext_vector_type(8))) short bf16x8;
typedef __attribute__((ext_vector_type(4))) float f32x4;

__device__ __forceinline__ ushort f2bf(float x) {
  union { float f; uint32_t u; } c; c.f = x;
  uint32_t r = (c.u + 0x7fffu + ((c.u >> 16) & 1u)) >> 16;
  return (ushort)r;
}

// ---------------- prep: fp32 row norms, fp32 diag, bf16 normalized copies ----
__global__ __launch_bounds__(256) void prep_kernel(const float* __restrict__ V,
                                                   const float* __restrict__ U,
                                                   ushort* __restrict__ Vn,
                                                   ushort* __restrict__ Un,
                                                   float* __restrict__ diag,
                                                   float* __restrict__ row_sum,
                                                   float* __restrict__ col_sum) {
  const int row = blockIdx.x * 4 + (threadIdx.x >> 6);
  const int l = threadIdx.x & 63;
  const float4* v4 = (const float4*)(V + (size_t)row * DIM) + l * 2;
  const float4* u4 = (const float4*)(U + (size_t)row * DIM) + l * 2;
  float4 a0 = v4[0], a1 = v4[1];
  float4 b0 = u4[0], b1 = u4[1];
  float sv = a0.x*a0.x + a0.y*a0.y + a0.z*a0.z + a0.w*a0.w
           + a1.x*a1.x + a1.y*a1.y + a1.z*a1.z + a1.w*a1.w;
  float su = b0.x*b0.x + b0.y*b0.y + b0.z*b0.z + b0.w*b0.w
           + b1.x*b1.x + b1.y*b1.y + b1.z*b1.z + b1.w*b1.w;
  float sd = a0.x*b0.x + a0.y*b0.y + a0.z*b0.z + a0.w*b0.w
           + a1.x*b1.x + a1.y*b1.y + a1.z*b1.z + a1.w*b1.w;
#pragma unroll
  for (int m = 1; m < 64; m <<= 1) {
    sv += __shfl_xor(sv, m, 64);
    su += __shfl_xor(su, m, 64);
    sd += __shfl_xor(sd, m, 64);
  }
  const float rv = 1.0f / fmaxf(sqrtf(sv), 1e-8f);
  const float ru = 1.0f / fmaxf(sqrtf(su), 1e-8f);
  if (l == 0) {
    diag[row] = sd * rv * ru * 10.0f;
    row_sum[row] = 0.0f;
    col_sum[row] = 0.0f;
  }

  const float av[8] = {a0.x, a0.y, a0.z, a0.w, a1.x, a1.y, a1.z, a1.w};
  const float bv[8] = {b0.x, b0.y, b0.z, b0.w, b1.x, b1.y, b1.z, b1.w};
  union { ushort us[8]; uint4 q; } pv, pu;
#pragma unroll
  for (int j = 0; j < 8; ++j) {
    pv.us[j] = f2bf(av[j] * rv);
    pu.us[j] = f2bf(bv[j] * ru);
  }
  *(uint4*)(Vn + (size_t)row * DIM + l * 8) = pv.q;
  *(uint4*)(Un + (size_t)row * DIM + l * 8) = pu.q;
}

// ---- 256x256 GEMM (bf16 MFMA) + exp(sim-10) + row/col sums ----
// R10 known-best structure (restored verbatim after fusion experiments
// R11/R12 proved net-negative):
// 16 waves / 4 per SIMD (acc 64 AGPR + 64 VGPR = exactly the 128-reg tier),
// single-barrier boundary per K-tile:
//   s_waitcnt vmcnt(0) lgkmcnt(0) ; s_barrier ; stage(j+2 -> buf b)
// lgkm0-before-bar => all waves' reads of buf b retired => staging b after
// the bar is WAR-safe. vmcnt(0)-before-bar => every thread's tile-j+1 loads
// landed => reads of buf b^1 after the bar are safe. Staged loads fly across
// the whole next K-tile; drained by the NEXT boundary's cold vmcnt(0).
// 8 barriers per block. L2-residency map: xcd owns fixed 4-ct stripe
// (B 1 MB L2-resident for the whole kernel); rt streams 8/round.
__global__ __launch_bounds__(1024, 4) void gemm_lse_kernel(const ushort* __restrict__ Vn,
                                                           const ushort* __restrict__ Un,
                                                           float* __restrict__ row_sum,
                                                           float* __restrict__ col_sum) {
  // buf b at b*65536: A[256][64] @0 (32K), B[256][64] @32768 (32K)
  __shared__ ushort Tile[65536];   // 128 KiB

  const int tid  = threadIdx.x;
  const int lane = tid & 63;
  const int wid  = tid >> 6;       // 0..15
  const int wr   = wid >> 2;       // 0..3 (64-row band)
  const int wc   = wid & 3;        // 0..3 (64-col band)
  const int l15  = lane & 15;
  const int lhi  = lane >> 4;      // 0..3
  const int sw7  = l15 & 7;

  // L2-residency map (R6): xcd owns fixed 4-ct stripe; rt streams 8/round
  const int bid  = blockIdx.x;
  const int xcd  = bid & 7;
  const int x    = bid >> 3;               // 0..127
  const int rt   = x >> 2;                 // 0..31
  const int ct   = xcd * 4 + (x & 3);      // fixed stripe
  const int br   = rt << 8;
  const int bc   = ct << 8;

  // ---- staging geometry: per matrix per K-tile = 2 issues x 1024 thr x 16B ----
  const int rr  = tid >> 3;                // 0..127
  const int seg = (tid & 7) ^ (rr & 7);    // inverse-swizzled source seg
  const ushort* gA[2]; const ushort* gB[2];
#pragma unroll
  for (int i = 0; i < 2; ++i) {
    gA[i] = Vn + (size_t)(br + i * 128 + rr) * DIM + seg * 8;
    gB[i] = Un + (size_t)(bc + i * 128 + rr) * DIM + seg * 8;
  }

  auto stg4 = [&](int buf, int kt) {   // whole K-tile kt -> buf (4 glds/thread)
#pragma unroll
    for (int i = 0; i < 2; ++i)
      __builtin_amdgcn_global_load_lds(
          (const __attribute__((address_space(1))) unsigned int*)(gA[i] + kt * 64),
          (__attribute__((address_space(3))) unsigned int*)((char*)Tile + buf * 65536 + i * 16384 + wid * 1024),
          16, 0, 0);
#pragma unroll
    for (int i = 0; i < 2; ++i)
      __builtin_amdgcn_global_load_lds(
          (const __attribute__((address_space(1))) unsigned int*)(gB[i] + kt * 64),
          (__attribute__((address_space(3))) unsigned int*)((char*)Tile + buf * 65536 + 32768 + i * 16384 + wid * 1024),
          16, 0, 0);
  };

  // ---- LDS read bases; physical slot = ((kk<<2)|lhi) ^ sw7 ----
  const char* TB = (const char*)Tile;
  const int sl0  = ((0 | lhi) ^ sw7) * 16;
  const int sl1  = ((4 | lhi) ^ sw7) * 16;
  const int aoff = (wr * 64 + l15) * 128;
  const int boff = (wc * 64 + l15) * 128;
  const char* pA[2] = { TB + aoff,          TB + 65536 + aoff };
  const char* pB[2] = { TB + 32768 + boff,  TB + 98304 + boff };

  f32x4 acc[4][4];
#pragma unroll
  for (int m = 0; m < 4; ++m)
#pragma unroll
    for (int n = 0; n < 4; ++n) acc[m][n] = (f32x4){0.f, 0.f, 0.f, 0.f};

  // prologue: tiles 0,1 staged (8 glds); tile0 landed at vmcnt(4)
  stg4(0, 0); stg4(1, 1);
  asm volatile("s_waitcnt vmcnt(4)" ::: "memory");
  __builtin_amdgcn_s_barrier();
  asm volatile("" ::: "memory");

#pragma unroll
  for (int j = 0; j < NKT; ++j) {
    const int b = j & 1;

    bf16x8 A0[4], B0[4], A1[4], B1[4];
    // kk0: read + 16 MFMA (compiler interleaves with counted lgkm)
#pragma unroll
    for (int m = 0; m < 4; ++m) A0[m] = *(const bf16x8*)(pA[b] + m * 2048 + sl0);
#pragma unroll
    for (int n = 0; n < 4; ++n) B0[n] = *(const bf16x8*)(pB[b] + n * 2048 + sl0);
    __builtin_amdgcn_s_setprio(1);
#pragma unroll
    for (int m = 0; m < 4; ++m)
#pragma unroll
      for (int n = 0; n < 4; ++n)
        acc[m][n] = __builtin_amdgcn_mfma_f32_16x16x32_bf16(A0[m], B0[n], acc[m][n], 0, 0, 0);
    __builtin_amdgcn_s_setprio(0);

    // kk1: read + 16 MFMA
#pragma unroll
    for (int m = 0; m < 4; ++m) A1[m] = *(const bf16x8*)(pA[b] + m * 2048 + sl1);
#pragma unroll
    for (int n = 0; n < 4; ++n) B1[n] = *(const bf16x8*)(pB[b] + n * 2048 + sl1);
    __builtin_amdgcn_s_setprio(1);
#pragma unroll
    for (int m = 0; m < 4; ++m)
#pragma unroll
      for (int n = 0; n < 4; ++n)
        acc[m][n] = __builtin_amdgcn_mfma_f32_16x16x32_bf16(A1[m], B1[n], acc[m][n], 0, 0, 0);
    __builtin_amdgcn_s_setprio(0);

    // ---- single-barrier boundary ----
    if (j + 2 < NKT) {
      asm volatile("s_waitcnt vmcnt(0) lgkmcnt(0)" ::: "memory");  // cold: loads 1 K-tile old + this tile's reads
      __builtin_amdgcn_s_barrier();
      asm volatile("" ::: "memory");
      stg4(b, j + 2);                                              // WAR-safe after bar; flies across next tile
    } else if (j == NKT - 2) {
      asm volatile("s_waitcnt vmcnt(0) lgkmcnt(0)" ::: "memory");  // tile 7 landed
      __builtin_amdgcn_s_barrier();
      asm volatile("" ::: "memory");
    }
    // j == NKT-1: fall through to epilogue
  }

  // ---- epilogue: exp(sim-10), row/col partial sums ----
  float* Red = (float*)Tile;

#pragma unroll
  for (int m = 0; m < 4; ++m)
#pragma unroll
    for (int n = 0; n < 4; ++n) {
      f32x4 v = acc[m][n];
#pragma unroll
      for (int r = 0; r < 4; ++r) v[r] = __builtin_amdgcn_exp2f((v[r] - 1.0f) * C_EXPSCALE);
      acc[m][n] = v;
    }

  __syncthreads();   // all frag reads done before Red overwrites Tile

  // rows: row_local = wr*64 + m*16 + lhi*4 + r; sum over wave's 64 cols
#pragma unroll
  for (int m = 0; m < 4; ++m)
#pragma unroll
    for (int r = 0; r < 4; ++r) {
      float s = acc[m][0][r] + acc[m][1][r] + acc[m][2][r] + acc[m][3][r];
      s += __shfl_xor(s, 1, 64);
      s += __shfl_xor(s, 2, 64);
      s += __shfl_xor(s, 4, 64);
      s += __shfl_xor(s, 8, 64);
      if (l15 == 0) Red[wc * 256 + wr * 64 + m * 16 + lhi * 4 + r] = s;
    }
  // cols: col_local = wc*64 + n*16 + l15; sum over wave's 64 rows
#pragma unroll
  for (int n = 0; n < 4; ++n) {
    float s = 0.f;
#pragma unroll
    for (int m = 0; m < 4; ++m)
      s += acc[m][n][0] + acc[m][n][1] + acc[m][n][2] + acc[m][n][3];
    s += __shfl_xor(s, 16, 64);
    s += __shfl_xor(s, 32, 64);
    if (lane < 16) Red[1024 + wr * 256 + wc * 64 + n * 16 + lane] = s;
  }
  __syncthreads();

  if (tid < 256) {
    float s = Red[tid] + Red[256 + tid] + Red[512 + tid] + Red[768 + tid];
    atomicAdd(&row_sum[br + tid], s);
  } else if (tid < 512) {
    const int c = tid - 256;
    float s = Red[1024 + c] + Red[1280 + c] + Red[1536 + c] + Red[1792 + c];
    atomicAdd(&col_sum[bc + c], s);
  }
}

// ---------------- finalize ----------------
__global__ __launch_bounds__(1024) void finalize_kernel(const float* __restrict__ row_sum,
                                                        const float* __restrict__ col_sum,
                                                        const float* __restrict__ diag,
                                                        float* __restrict__ out) {
  __shared__ float sred[1024];
  float acc = 0.0f;
  for (int i = threadIdx.x; i < N_ROWS; i += 1024) {
    const float lse_r = 10.0f + logf(row_sum[i]);
    const float lse_c = 10.0f + logf(col_sum[i]);
    acc += 0.75f * lse_r + 0.25f * lse_c - diag[i];
  }
  sred[threadIdx.x] = acc;
  __syncthreads();
  for (int s = 512; s > 0; s >>= 1) {
    if ((int)threadIdx.x < s) sred[threadIdx.x] += sred[threadIdx.x + s];
    __syncthreads();
  }
  if (threadIdx.x == 0) out[0] = sred[0] / (float)N_ROWS;
}

extern "C" void kernel_launch(void* const* d_in, const int* in_sizes, int n_in,
                              void* d_out, int out_size, void* d_ws, size_t ws_size,
                              hipStream_t stream) {
  const float* V = (const float*)d_in[0];
  const float* U = (const float*)d_in[1];
  float* out = (float*)d_out;

  char* ws = (char*)d_ws;
  ushort* Vn      = (ushort*)(ws);
  ushort* Un      = (ushort*)(ws + 8388608);
  float*  diag    = (float*)(ws + 16777216);
  float*  row_sum = (float*)(ws + 16777216 + 32768);
  float*  col_sum = (float*)(ws + 16777216 + 65536);

  prep_kernel<<<N_ROWS / 4, 256, 0, stream>>>(V, U, Vn, Un, diag, row_sum, col_sum);
  gemm_lse_kernel<<<(N_ROWS / 256) * (N_ROWS / 256), 1024, 0, stream>>>(Vn, Un, row_sum, col_sum);
  finalize_kernel<<<1, 1024, 0, stream>>>(row_sum, col_sum, diag, out);
}